// Round 9
// baseline (72.501 us; speedup 1.0000x reference)
//
#include <hip/hip_runtime.h>
#include <stdint.h>

typedef __attribute__((ext_vector_type(8))) short bf16x8;
typedef __attribute__((ext_vector_type(8))) char  char8;
typedef __attribute__((ext_vector_type(4))) float f32x4;
typedef __attribute__((ext_vector_type(4))) int   i32x4;

#define SU      (4.5f / 127.0f)     // shared int8 scale for both h1 tables
#define INV_SU  (127.0f / 4.5f)

__device__ __forceinline__ unsigned short f2bf(float f) {
    uint32_t u = __builtin_bit_cast(uint32_t, f);
    uint32_t r = (u + 0x7FFFu + ((u >> 16) & 1u)) >> 16;  // RTN-even
    return (unsigned short)r;
}

__device__ __forceinline__ float bf2f(unsigned short u) {
    return __builtin_bit_cast(float, (uint32_t)u << 16);
}

__device__ __forceinline__ bf16x8 cvt8(f32x4 a, f32x4 b) {
    bf16x8 v;
#pragma unroll
    for (int i = 0; i < 4; ++i) v[i] = (short)f2bf(a[i]);
#pragma unroll
    for (int i = 0; i < 4; ++i) v[4 + i] = (short)f2bf(b[i]);
    return v;
}

// swizzled byte offset inside a [128][128] bf16 LDS tile (row = 256 B)
__device__ __forceinline__ unsigned swz256(int n, int kbyte) {
    return ((unsigned)(n * 256 + kbyte)) ^ (unsigned)((n & 7) << 4);
}

// ---------------------------------------------------------------------------
// precompute_h1 v3: PERSISTENT blocks. First buN blocks process all user
// row-tiles grid-stride; the rest process movie tiles. W1-half staged into
// LDS ONCE per block; no barrier inside the tile loop -> compiler pipelines
// next-tile z-loads over current-tile MFMA. Same per-row arithmetic as R7
// (identical fragments, ks order, quant epilogue) -> bit-identical output.
// 128 rows/tile (4 waves x 32 rows, acc 2x8).
// ---------------------------------------------------------------------------
__global__ __launch_bounds__(256) void precompute_h1(
    const float* __restrict__ zu, const float* __restrict__ zm,
    const float* __restrict__ W1, const float* __restrict__ b1,
    char* __restrict__ h1u8, char* __restrict__ h1m8,
    int Mu, int Mm, int buN, int bmN)
{
    __shared__ __align__(16) char Bs[32768];
    const int tid  = threadIdx.x;
    const int wid  = tid >> 6;
    const int lane = tid & 63;
    const int g    = lane >> 4;
    const int lm   = lane & 15;

    const bool isU = (int)blockIdx.x < buN;
    const float* z = isU ? zu : zm;
    char* h1       = isU ? h1u8 : h1m8;
    const int M    = isU ? Mu : Mm;
    const int koff = isU ? 0 : 128;
    const int bloc = isU ? (int)blockIdx.x : (int)blockIdx.x - buN;
    const int nblk = isU ? buN : bmN;
    const int ntiles = (M + 127) / 128;

    // stage W1[:, koff:koff+128] f32 -> bf16 swizzled (once per block)
#pragma unroll
    for (int it = 0; it < 8; ++it) {
        int c  = it * 256 + tid;
        int n  = c >> 4;
        int kc = c & 15;
        const float* src = W1 + n * 256 + koff + kc * 8;
        f32x4 a = *reinterpret_cast<const f32x4*>(src);
        f32x4 b = *reinterpret_cast<const f32x4*>(src + 4);
        *reinterpret_cast<bf16x8*>(&Bs[swz256(n, kc * 16)]) = cvt8(a, b);
    }
    __syncthreads();

    // b1 for this lane's n-values: n = nt*16 + g*4 + r
    f32x4 b1q[8];
#pragma unroll
    for (int nt = 0; nt < 8; ++nt) {
        f32x4 t = *reinterpret_cast<const f32x4*>(b1 + nt * 16 + g * 4);
#pragma unroll
        for (int r = 0; r < 4; ++r) b1q[nt][r] = 0.5f * t[r];
    }

    for (int tile = bloc; tile < ntiles; tile += nblk) {
        const int rbase = tile * 128 + wid * 32;

        f32x4 acc[2][8];
#pragma unroll
        for (int mt = 0; mt < 2; ++mt)
#pragma unroll
            for (int nt = 0; nt < 8; ++nt) acc[mt][nt] = f32x4{0.f, 0.f, 0.f, 0.f};

#pragma unroll
        for (int ks = 0; ks < 4; ++ks) {
            bf16x8 a[2];
#pragma unroll
            for (int mt = 0; mt < 2; ++mt) {
                int r = rbase + mt * 16 + lm;
                r = r < M ? r : M - 1;
                const float* p = z + (size_t)r * 128 + ks * 32 + g * 8;
                f32x4 x0 = *reinterpret_cast<const f32x4*>(p);
                f32x4 x1 = *reinterpret_cast<const f32x4*>(p + 4);
                a[mt] = cvt8(x0, x1);
            }
            const int kbyte = (ks * 32 + g * 8) * 2;
#pragma unroll
            for (int nt = 0; nt < 8; ++nt) {
                bf16x8 bfr = *reinterpret_cast<const bf16x8*>(&Bs[swz256(nt * 16 + lm, kbyte)]);
#pragma unroll
                for (int mt = 0; mt < 2; ++mt)
                    acc[mt][nt] = __builtin_amdgcn_mfma_f32_16x16x32_bf16(
                        bfr, a[mt], acc[mt][nt], 0, 0, 0);   // SWAPPED: D' = D^T
            }
        }

        // store int8: lane holds m = rbase + mt*16 + lm ; n = nt*16 + g*4 + r
#pragma unroll
        for (int mt = 0; mt < 2; ++mt) {
            const int m = rbase + mt * 16 + lm;
            if (m >= M) continue;
#pragma unroll
            for (int nt = 0; nt < 8; ++nt) {
                uint32_t p = 0;
#pragma unroll
                for (int r = 0; r < 4; ++r) {
                    float h  = acc[mt][nt][r] + b1q[nt][r];
                    float qf = fmaxf(-127.f, fminf(127.f, __builtin_rintf(h * INV_SU)));
                    int   q  = (int)qf;
                    p |= (uint32_t)(q & 0xff) << (8 * r);
                }
                *reinterpret_cast<uint32_t*>(h1 + (size_t)m * 128 + nt * 16 + g * 4) = p;
            }
        }
    }
}

// ---------------------------------------------------------------------------
// edge_score: out[e] = SU * ( max(uq+mq, 0) . w2 ) + b2  (int8 gather both
// sides, shared scale -> integer add/relu, w2 pre-scaled by SU).
// 16 lanes per 8 edges; each h1 row = 128 B = one cache line.
// ---------------------------------------------------------------------------
__global__ __launch_bounds__(256) void edge_score(
    const char* __restrict__ h1u8, const char* __restrict__ h1m8,
    const int* __restrict__ row, const int* __restrict__ col,
    const float* __restrict__ W2, const float* __restrict__ b2,
    float* __restrict__ out, int nE)
{
    const int tid = blockIdx.x * 256 + threadIdx.x;
    const int g   = tid >> 4;
    const int l   = tid & 15;
    const int e0  = g * 8;
    if (e0 >= nE) return;

    float w2s[8];
    {
        f32x4 c0 = *reinterpret_cast<const f32x4*>(W2 + l * 8);
        f32x4 c1 = *reinterpret_cast<const f32x4*>(W2 + l * 8 + 4);
#pragma unroll
        for (int j = 0; j < 4; ++j) { w2s[j] = c0[j] * SU; w2s[4 + j] = c1[j] * SU; }
    }
    const float b2s = b2[0];

    int ridx[8], cidx[8];
    if (e0 + 8 <= nE) {
        i32x4 r0 = __builtin_nontemporal_load(reinterpret_cast<const i32x4*>(row + e0));
        i32x4 r1 = __builtin_nontemporal_load(reinterpret_cast<const i32x4*>(row + e0 + 4));
        i32x4 c0 = __builtin_nontemporal_load(reinterpret_cast<const i32x4*>(col + e0));
        i32x4 c1 = __builtin_nontemporal_load(reinterpret_cast<const i32x4*>(col + e0 + 4));
#pragma unroll
        for (int j = 0; j < 4; ++j) { ridx[j] = r0[j]; ridx[4 + j] = r1[j]; }
#pragma unroll
        for (int j = 0; j < 4; ++j) { cidx[j] = c0[j]; cidx[4 + j] = c1[j]; }
    } else {
#pragma unroll
        for (int j = 0; j < 8; ++j) {
            int e = e0 + j;
            e = e < nE ? e : nE - 1;
            ridx[j] = row[e];
            cidx[j] = col[e];
        }
    }

    // issue all 16 gathers back-to-back, then fence the scheduler
    char8 u[8], m[8];
#pragma unroll
    for (int j = 0; j < 8; ++j)
        u[j] = *reinterpret_cast<const char8*>(h1u8 + (size_t)ridx[j] * 128 + l * 8);
#pragma unroll
    for (int j = 0; j < 8; ++j)
        m[j] = *reinterpret_cast<const char8*>(h1m8 + (size_t)cidx[j] * 128 + l * 8);
    __builtin_amdgcn_sched_barrier(0);

    float s[8];
#pragma unroll
    for (int j = 0; j < 8; ++j) {
        float acc = 0.f;
#pragma unroll
        for (int q = 0; q < 8; ++q) {
            int su = (int)u[j][q] + (int)m[j][q];
            su = su > 0 ? su : 0;
            acc = fmaf((float)su, w2s[q], acc);
        }
        acc += __shfl_xor(acc, 1);
        acc += __shfl_xor(acc, 2);
        acc += __shfl_xor(acc, 4);
        acc += __shfl_xor(acc, 8);
        s[j] = acc + b2s;
    }

    // lane j stores edge e0+j (coalesced 32 B per group)
    float v = 0.f;
#pragma unroll
    for (int j = 0; j < 8; ++j) v = (l == j) ? s[j] : v;
    const int e = e0 + l;
    if (l < 8 && e < nE) __builtin_nontemporal_store(v, out + e);
}

// ---------------------------------------------------------------------------
// fallback (no workspace): round-0 fused kernel, f32 gather path
// ---------------------------------------------------------------------------
__device__ __forceinline__ unsigned swzB(int n, int kbyte) {
    return ((unsigned)(n * 512 + kbyte)) ^ (unsigned)((n & 7) << 4);
}

__global__ __launch_bounds__(256, 2) void edge_mlp_fallback(
    const float* __restrict__ z_user, const float* __restrict__ z_movie,
    const int* __restrict__ row, const int* __restrict__ col,
    const float* __restrict__ W1, const float* __restrict__ b1,
    const float* __restrict__ W2, const float* __restrict__ b2,
    float* __restrict__ out, int nE, int ntiles)
{
    __shared__ __align__(16) char Bs[65536];
    const int tid  = threadIdx.x;
    const int wid  = tid >> 6;
    const int lane = tid & 63;
    const int g    = lane >> 4;
    const int lm   = lane & 15;

#pragma unroll
    for (int it = 0; it < 16; ++it) {
        int c  = it * 256 + tid;
        int n  = c >> 5;
        int kc = c & 31;
        const float* src = W1 + n * 256 + kc * 8;
        f32x4 a = *reinterpret_cast<const f32x4*>(src);
        f32x4 b = *reinterpret_cast<const f32x4*>(src + 4);
        *reinterpret_cast<bf16x8*>(&Bs[swzB(n, kc * 16)]) = cvt8(a, b);
    }
    __syncthreads();

    float b1v[8], w2v[8];
#pragma unroll
    for (int nt = 0; nt < 8; ++nt) {
        int n = nt * 16 + lm;
        b1v[nt] = b1[n];
        w2v[nt] = W2[n];
    }
    const float b2s = b2[0];

    for (int tile = blockIdx.x; tile < ntiles; tile += gridDim.x) {
        const int ebase = tile * 256 + wid * 64;
        int re[4], ce[4];
#pragma unroll
        for (int mt = 0; mt < 4; ++mt) {
            int e = ebase + mt * 16 + lm;
            e = e < nE ? e : nE - 1;
            re[mt] = row[e];
            ce[mt] = col[e];
        }
        f32x4 acc[4][8];
#pragma unroll
        for (int mt = 0; mt < 4; ++mt)
#pragma unroll
            for (int nt = 0; nt < 8; ++nt) acc[mt][nt] = f32x4{0.f, 0.f, 0.f, 0.f};
#pragma unroll
        for (int half = 0; half < 2; ++half) {
#pragma unroll
            for (int ks = 0; ks < 4; ++ks) {
                bf16x8 a[4];
#pragma unroll
                for (int mt = 0; mt < 4; ++mt) {
                    const float* p = (half ? z_movie + (size_t)ce[mt] * 128
                                           : z_user + (size_t)re[mt] * 128) + ks * 32 + g * 8;
                    f32x4 x0 = *reinterpret_cast<const f32x4*>(p);
                    f32x4 x1 = *reinterpret_cast<const f32x4*>(p + 4);
                    a[mt] = cvt8(x0, x1);
                }
                const int kbyte = (half * 128 + ks * 32 + g * 8) * 2;
#pragma unroll
                for (int nt = 0; nt < 8; ++nt) {
                    bf16x8 bfr = *reinterpret_cast<const bf16x8*>(&Bs[swzB(nt * 16 + lm, kbyte)]);
#pragma unroll
                    for (int mt = 0; mt < 4; ++mt)
                        acc[mt][nt] = __builtin_amdgcn_mfma_f32_16x16x32_bf16(
                            a[mt], bfr, acc[mt][nt], 0, 0, 0);
                }
            }
        }
#pragma unroll
        for (int mt = 0; mt < 4; ++mt) {
#pragma unroll
            for (int r = 0; r < 4; ++r) {
                float s = 0.f;
#pragma unroll
                for (int nt = 0; nt < 8; ++nt)
                    s += fmaxf(acc[mt][nt][r] + b1v[nt], 0.f) * w2v[nt];
                s += __shfl_xor(s, 8);
                s += __shfl_xor(s, 4);
                s += __shfl_xor(s, 2);
                s += __shfl_xor(s, 1);
                if (lm == 0) {
                    int e = ebase + mt * 16 + g * 4 + r;
                    if (e < nE) out[e] = s + b2s;
                }
            }
        }
    }
}

extern "C" void kernel_launch(void* const* d_in, const int* in_sizes, int n_in,
                              void* d_out, int out_size, void* d_ws, size_t ws_size,
                              hipStream_t stream) {
    const float* z_user  = (const float*)d_in[0];
    const float* z_movie = (const float*)d_in[1];
    const int*   row     = (const int*)d_in[2];
    const int*   col     = (const int*)d_in[3];
    const float* W1      = (const float*)d_in[4];
    const float* b1      = (const float*)d_in[5];
    const float* W2      = (const float*)d_in[6];
    const float* b2      = (const float*)d_in[7];
    float*       out     = (float*)d_out;

    const int nE = in_sizes[2];
    const int Mu = in_sizes[0] / 128;   // N_USERS
    const int Mm = in_sizes[1] / 128;   // N_MOVIES

    const size_t need = ((size_t)Mu + (size_t)Mm) * 128;   // both tables int8

    if (ws_size >= need) {
        char* h1u8 = (char*)d_ws;
        char* h1m8 = h1u8 + (size_t)Mu * 128;

        // persistent split grid: ~2.25 blocks/CU, ~3 tiles per block
        int buN = 256, bmN = 128;
        const int ntu = (Mu + 127) / 128;
        const int ntm = (Mm + 127) / 128;
        if (buN > ntu) buN = ntu;
        if (bmN > ntm) bmN = ntm;
        precompute_h1<<<buN + bmN, 256, 0, stream>>>(z_user, z_movie, W1, b1,
                                                     h1u8, h1m8, Mu, Mm, buN, bmN);

        const int nGroups = (nE + 7) / 8;
        const int blocks  = (nGroups * 16 + 255) / 256;
        edge_score<<<blocks, 256, 0, stream>>>(h1u8, h1m8, row, col,
                                               W2, b2, out, nE);
    } else {
        const int ntiles = (nE + 255) / 256;
        const int grid   = ntiles < 512 ? ntiles : 512;
        edge_mlp_fallback<<<grid, 256, 0, stream>>>(z_user, z_movie, row, col,
                                                    W1, b1, W2, b2, out, nE, ntiles);
    }
}

// Round 10
// 71.802 us; speedup vs baseline: 1.0097x; 1.0097x over previous
//
#include <hip/hip_runtime.h>
#include <stdint.h>

typedef __attribute__((ext_vector_type(8))) short bf16x8;
typedef __attribute__((ext_vector_type(8))) char  char8;
typedef __attribute__((ext_vector_type(4))) float f32x4;
typedef __attribute__((ext_vector_type(4))) int   i32x4;

#define SU      (4.5f / 127.0f)     // shared int8 scale for both h1 tables
#define INV_SU  (127.0f / 4.5f)

__device__ __forceinline__ unsigned short f2bf(float f) {
    uint32_t u = __builtin_bit_cast(uint32_t, f);
    uint32_t r = (u + 0x7FFFu + ((u >> 16) & 1u)) >> 16;  // RTN-even
    return (unsigned short)r;
}

__device__ __forceinline__ bf16x8 cvt8(f32x4 a, f32x4 b) {
    bf16x8 v;
#pragma unroll
    for (int i = 0; i < 4; ++i) v[i] = (short)f2bf(a[i]);
#pragma unroll
    for (int i = 0; i < 4; ++i) v[4 + i] = (short)f2bf(b[i]);
    return v;
}

// ---------------------------------------------------------------------------
// w1cvt: one-time W1 f32 -> bf16 in B-FRAGMENT order:
//   chunk idx = ((half*8 + nt)*4 + ks)*64 + lane   (16 B per chunk)
//   chunk holds W1[nt*16 + (lane&15)][half*128 + ks*32 + (lane>>4)*8 .. +8]
// One wave's per-(nt,ks) fragment load is then a single coalesced 1 KB read.
// ---------------------------------------------------------------------------
__global__ void w1cvt(const float* __restrict__ W1, unsigned short* __restrict__ w1bf) {
    const int idx  = blockIdx.x * 256 + threadIdx.x;   // 0..4095
    const int half = idx >> 11;
    const int rem  = idx & 2047;
    const int nt   = rem >> 8;
    const int ks   = (rem >> 6) & 3;
    const int lane = rem & 63;
    const int lm   = lane & 15;
    const int g    = lane >> 4;
    const float* src = W1 + (nt * 16 + lm) * 256 + half * 128 + ks * 32 + g * 8;
    f32x4 a = *reinterpret_cast<const f32x4*>(src);
    f32x4 b = *reinterpret_cast<const f32x4*>(src + 4);
    *reinterpret_cast<bf16x8*>(w1bf + (size_t)idx * 8) = cvt8(a, b);
}

// ---------------------------------------------------------------------------
// precompute_h1 v4: NO LDS, NO barrier. B-fragments read per-(nt,ks) from the
// L2-resident w1bf (64 KB/half, broadcast across waves). Same fragment
// geometry / swapped-MFMA / quant epilogue as R7 -> bit-identical h1 tables.
// 128 rows/block (4 waves x 32 rows, acc 2x8), pure streaming blocks.
// ---------------------------------------------------------------------------
__global__ __launch_bounds__(256) void precompute_h1(
    const float* __restrict__ zu, const float* __restrict__ zm,
    const unsigned short* __restrict__ w1bf, const float* __restrict__ b1,
    char* __restrict__ h1u8, char* __restrict__ h1m8,
    int Mu, int Mm, int bu)
{
    const int tid  = threadIdx.x;
    const int wid  = tid >> 6;
    const int lane = tid & 63;
    const int g    = lane >> 4;
    const int lm   = lane & 15;

    const bool isU = (int)blockIdx.x < bu;
    const float* z = isU ? zu : zm;
    char* h1       = isU ? h1u8 : h1m8;
    const int M    = isU ? Mu : Mm;
    const unsigned short* wb = w1bf + (isU ? 0 : (size_t)2048 * 8);  // half offset
    const int rbase = (isU ? blockIdx.x : blockIdx.x - bu) * 128 + wid * 32;

    f32x4 acc[2][8];
#pragma unroll
    for (int mt = 0; mt < 2; ++mt)
#pragma unroll
        for (int nt = 0; nt < 8; ++nt) acc[mt][nt] = f32x4{0.f, 0.f, 0.f, 0.f};

#pragma unroll
    for (int ks = 0; ks < 4; ++ks) {
        bf16x8 a[2];
#pragma unroll
        for (int mt = 0; mt < 2; ++mt) {
            int r = rbase + mt * 16 + lm;
            r = r < M ? r : M - 1;
            const float* p = z + (size_t)r * 128 + ks * 32 + g * 8;
            f32x4 x0 = *reinterpret_cast<const f32x4*>(p);
            f32x4 x1 = *reinterpret_cast<const f32x4*>(p + 4);
            a[mt] = cvt8(x0, x1);
        }
#pragma unroll
        for (int nt = 0; nt < 8; ++nt) {
            bf16x8 bfr = *reinterpret_cast<const bf16x8*>(
                wb + ((size_t)(nt * 4 + ks) * 64 + lane) * 8);
#pragma unroll
            for (int mt = 0; mt < 2; ++mt)
                acc[mt][nt] = __builtin_amdgcn_mfma_f32_16x16x32_bf16(
                    bfr, a[mt], acc[mt][nt], 0, 0, 0);   // SWAPPED: D' = D^T
        }
    }

    // b1 loaded in epilogue (shortens main-loop register liveness)
    f32x4 b1q[8];
#pragma unroll
    for (int nt = 0; nt < 8; ++nt) {
        f32x4 t = *reinterpret_cast<const f32x4*>(b1 + nt * 16 + g * 4);
#pragma unroll
        for (int r = 0; r < 4; ++r) b1q[nt][r] = 0.5f * t[r];
    }

    // store int8: lane holds m = rbase + mt*16 + lm ; n = nt*16 + g*4 + r
#pragma unroll
    for (int mt = 0; mt < 2; ++mt) {
        const int m = rbase + mt * 16 + lm;
        if (m >= M) continue;
#pragma unroll
        for (int nt = 0; nt < 8; ++nt) {
            uint32_t p = 0;
#pragma unroll
            for (int r = 0; r < 4; ++r) {
                float h  = acc[mt][nt][r] + b1q[nt][r];
                float qf = fmaxf(-127.f, fminf(127.f, __builtin_rintf(h * INV_SU)));
                int   q  = (int)qf;
                p |= (uint32_t)(q & 0xff) << (8 * r);
            }
            *reinterpret_cast<uint32_t*>(h1 + (size_t)m * 128 + nt * 16 + g * 4) = p;
        }
    }
}

// ---------------------------------------------------------------------------
// edge_score: out[e] = SU * ( max(uq+mq, 0) . w2 ) + b2  (unchanged from R7)
// ---------------------------------------------------------------------------
__global__ __launch_bounds__(256) void edge_score(
    const char* __restrict__ h1u8, const char* __restrict__ h1m8,
    const int* __restrict__ row, const int* __restrict__ col,
    const float* __restrict__ W2, const float* __restrict__ b2,
    float* __restrict__ out, int nE)
{
    const int tid = blockIdx.x * 256 + threadIdx.x;
    const int g   = tid >> 4;
    const int l   = tid & 15;
    const int e0  = g * 8;
    if (e0 >= nE) return;

    float w2s[8];
    {
        f32x4 c0 = *reinterpret_cast<const f32x4*>(W2 + l * 8);
        f32x4 c1 = *reinterpret_cast<const f32x4*>(W2 + l * 8 + 4);
#pragma unroll
        for (int j = 0; j < 4; ++j) { w2s[j] = c0[j] * SU; w2s[4 + j] = c1[j] * SU; }
    }
    const float b2s = b2[0];

    int ridx[8], cidx[8];
    if (e0 + 8 <= nE) {
        i32x4 r0 = __builtin_nontemporal_load(reinterpret_cast<const i32x4*>(row + e0));
        i32x4 r1 = __builtin_nontemporal_load(reinterpret_cast<const i32x4*>(row + e0 + 4));
        i32x4 c0 = __builtin_nontemporal_load(reinterpret_cast<const i32x4*>(col + e0));
        i32x4 c1 = __builtin_nontemporal_load(reinterpret_cast<const i32x4*>(col + e0 + 4));
#pragma unroll
        for (int j = 0; j < 4; ++j) { ridx[j] = r0[j]; ridx[4 + j] = r1[j]; }
#pragma unroll
        for (int j = 0; j < 4; ++j) { cidx[j] = c0[j]; cidx[4 + j] = c1[j]; }
    } else {
#pragma unroll
        for (int j = 0; j < 8; ++j) {
            int e = e0 + j;
            e = e < nE ? e : nE - 1;
            ridx[j] = row[e];
            cidx[j] = col[e];
        }
    }

    // issue all 16 gathers back-to-back, then fence the scheduler
    char8 u[8], m[8];
#pragma unroll
    for (int j = 0; j < 8; ++j)
        u[j] = *reinterpret_cast<const char8*>(h1u8 + (size_t)ridx[j] * 128 + l * 8);
#pragma unroll
    for (int j = 0; j < 8; ++j)
        m[j] = *reinterpret_cast<const char8*>(h1m8 + (size_t)cidx[j] * 128 + l * 8);
    __builtin_amdgcn_sched_barrier(0);

    float s[8];
#pragma unroll
    for (int j = 0; j < 8; ++j) {
        float acc = 0.f;
#pragma unroll
        for (int q = 0; q < 8; ++q) {
            int su = (int)u[j][q] + (int)m[j][q];
            su = su > 0 ? su : 0;
            acc = fmaf((float)su, w2s[q], acc);
        }
        acc += __shfl_xor(acc, 1);
        acc += __shfl_xor(acc, 2);
        acc += __shfl_xor(acc, 4);
        acc += __shfl_xor(acc, 8);
        s[j] = acc + b2s;
    }

    float v = 0.f;
#pragma unroll
    for (int j = 0; j < 8; ++j) v = (l == j) ? s[j] : v;
    const int e = e0 + l;
    if (l < 8 && e < nE) __builtin_nontemporal_store(v, out + e);
}

// ---------------------------------------------------------------------------
// fallback (no workspace): round-0 fused kernel, f32 gather path
// ---------------------------------------------------------------------------
__device__ __forceinline__ unsigned swzB(int n, int kbyte) {
    return ((unsigned)(n * 512 + kbyte)) ^ (unsigned)((n & 7) << 4);
}

__global__ __launch_bounds__(256, 2) void edge_mlp_fallback(
    const float* __restrict__ z_user, const float* __restrict__ z_movie,
    const int* __restrict__ row, const int* __restrict__ col,
    const float* __restrict__ W1, const float* __restrict__ b1,
    const float* __restrict__ W2, const float* __restrict__ b2,
    float* __restrict__ out, int nE, int ntiles)
{
    __shared__ __align__(16) char Bs[65536];
    const int tid  = threadIdx.x;
    const int wid  = tid >> 6;
    const int lane = tid & 63;
    const int g    = lane >> 4;
    const int lm   = lane & 15;

#pragma unroll
    for (int it = 0; it < 16; ++it) {
        int c  = it * 256 + tid;
        int n  = c >> 5;
        int kc = c & 31;
        const float* src = W1 + n * 256 + kc * 8;
        f32x4 a = *reinterpret_cast<const f32x4*>(src);
        f32x4 b = *reinterpret_cast<const f32x4*>(src + 4);
        *reinterpret_cast<bf16x8*>(&Bs[swzB(n, kc * 16)]) = cvt8(a, b);
    }
    __syncthreads();

    float b1v[8], w2v[8];
#pragma unroll
    for (int nt = 0; nt < 8; ++nt) {
        int n = nt * 16 + lm;
        b1v[nt] = b1[n];
        w2v[nt] = W2[n];
    }
    const float b2s = b2[0];

    for (int tile = blockIdx.x; tile < ntiles; tile += gridDim.x) {
        const int ebase = tile * 256 + wid * 64;
        int re[4], ce[4];
#pragma unroll
        for (int mt = 0; mt < 4; ++mt) {
            int e = ebase + mt * 16 + lm;
            e = e < nE ? e : nE - 1;
            re[mt] = row[e];
            ce[mt] = col[e];
        }
        f32x4 acc[4][8];
#pragma unroll
        for (int mt = 0; mt < 4; ++mt)
#pragma unroll
            for (int nt = 0; nt < 8; ++nt) acc[mt][nt] = f32x4{0.f, 0.f, 0.f, 0.f};
#pragma unroll
        for (int half = 0; half < 2; ++half) {
#pragma unroll
            for (int ks = 0; ks < 4; ++ks) {
                bf16x8 a[4];
#pragma unroll
                for (int mt = 0; mt < 4; ++mt) {
                    const float* p = (half ? z_movie + (size_t)ce[mt] * 128
                                           : z_user + (size_t)re[mt] * 128) + ks * 32 + g * 8;
                    f32x4 x0 = *reinterpret_cast<const f32x4*>(p);
                    f32x4 x1 = *reinterpret_cast<const f32x4*>(p + 4);
                    a[mt] = cvt8(x0, x1);
                }
                const int kbyte = (half * 128 + ks * 32 + g * 8) * 2;
#pragma unroll
                for (int nt = 0; nt < 8; ++nt) {
                    bf16x8 bfr = *reinterpret_cast<const bf16x8*>(&Bs[swzB(nt * 16 + lm, kbyte)]);
#pragma unroll
                    for (int mt = 0; mt < 4; ++mt)
                        acc[mt][nt] = __builtin_amdgcn_mfma_f32_16x16x32_bf16(
                            a[mt], bfr, acc[mt][nt], 0, 0, 0);
                }
            }
        }
#pragma unroll
        for (int mt = 0; mt < 4; ++mt) {
#pragma unroll
            for (int r = 0; r < 4; ++r) {
                float s = 0.f;
#pragma unroll
                for (int nt = 0; nt < 8; ++nt)
                    s += fmaxf(acc[mt][nt][r] + b1v[nt], 0.f) * w2v[nt];
                s += __shfl_xor(s, 8);
                s += __shfl_xor(s, 4);
                s += __shfl_xor(s, 2);
                s += __shfl_xor(s, 1);
                if (lm == 0) {
                    int e = ebase + mt * 16 + g * 4 + r;
                    if (e < nE) out[e] = s + b2s;
                }
            }
        }
    }
}

extern "C" void kernel_launch(void* const* d_in, const int* in_sizes, int n_in,
                              void* d_out, int out_size, void* d_ws, size_t ws_size,
                              hipStream_t stream) {
    const float* z_user  = (const float*)d_in[0];
    const float* z_movie = (const float*)d_in[1];
    const int*   row     = (const int*)d_in[2];
    const int*   col     = (const int*)d_in[3];
    const float* W1      = (const float*)d_in[4];
    const float* b1      = (const float*)d_in[5];
    const float* W2      = (const float*)d_in[6];
    const float* b2      = (const float*)d_in[7];
    float*       out     = (float*)d_out;

    const int nE = in_sizes[2];
    const int Mu = in_sizes[0] / 128;   // N_USERS
    const int Mm = in_sizes[1] / 128;   // N_MOVIES

    const size_t tblBytes = ((size_t)Mu + (size_t)Mm) * 128;   // int8 tables
    const size_t need     = tblBytes + 65536;                  // + w1bf

    if (ws_size >= need) {
        char* h1u8 = (char*)d_ws;
        char* h1m8 = h1u8 + (size_t)Mu * 128;
        unsigned short* w1bf = (unsigned short*)(h1u8 + tblBytes);

        w1cvt<<<16, 256, 0, stream>>>(W1, w1bf);

        const int bu = (Mu + 127) / 128;
        const int bm = (Mm + 127) / 128;
        precompute_h1<<<bu + bm, 256, 0, stream>>>(z_user, z_movie, w1bf, b1,
                                                   h1u8, h1m8, Mu, Mm, bu);

        const int nGroups = (nE + 7) / 8;
        const int blocks  = (nGroups * 16 + 255) / 256;
        edge_score<<<blocks, 256, 0, stream>>>(h1u8, h1m8, row, col,
                                               W2, b2, out, nE);
    } else {
        const int ntiles = (nE + 255) / 256;
        const int grid   = ntiles < 512 ? ntiles : 512;
        edge_mlp_fallback<<<grid, 256, 0, stream>>>(z_user, z_movie, row, col,
                                                    W1, b1, W2, b2, out, nE, ntiles);
    }
}

// Round 11
// 62.818 us; speedup vs baseline: 1.1541x; 1.1430x over previous
//
#include <hip/hip_runtime.h>
#include <stdint.h>

typedef __attribute__((ext_vector_type(8))) short bf16x8;
typedef __attribute__((ext_vector_type(8))) char  char8;
typedef __attribute__((ext_vector_type(4))) float f32x4;
typedef __attribute__((ext_vector_type(4))) int   i32x4;

#define SU      (4.5f / 127.0f)     // shared int8 scale for both h1 tables
#define INV_SU  (127.0f / 4.5f)
#define MAGIC   12582912.0f         // 1.5 * 2^23 : RNE int-round via add

__device__ __forceinline__ unsigned short f2bf(float f) {
    uint32_t u = __builtin_bit_cast(uint32_t, f);
    uint32_t r = (u + 0x7FFFu + ((u >> 16) & 1u)) >> 16;  // RTN-even
    return (unsigned short)r;
}

__device__ __forceinline__ bf16x8 cvt8(f32x4 a, f32x4 b) {
    bf16x8 v;
#pragma unroll
    for (int i = 0; i < 4; ++i) v[i] = (short)f2bf(a[i]);
#pragma unroll
    for (int i = 0; i < 4; ++i) v[4 + i] = (short)f2bf(b[i]);
    return v;
}

// swizzled byte offset inside a [128][128] bf16 LDS tile (row = 256 B)
__device__ __forceinline__ unsigned swz256(int n, int kbyte) {
    return ((unsigned)(n * 256 + kbyte)) ^ (unsigned)((n & 7) << 4);
}

// ---------------------------------------------------------------------------
// precompute_h1 v5: the R2-proven shell (LDS-staged W1-half, 256 rows/block,
// acc[4][8], NORMAL operand order) + int8 output via 3-VALU magic-quant:
//   t = fmaf(acc, INV_SU, b1h*INV_SU); c = clamp(t, +-127);
//   f = c + MAGIC  ->  low byte of bits(f) IS int8(rne(c))  -> store_byte.
// b1 == 0 here => q bit-identical to R7/R8's rintf path (absmax unchanged).
// D frag (normal order): row m = g*4+r (+mt*16), col n = nt*16+lm.
// ---------------------------------------------------------------------------
__global__ __launch_bounds__(256) void precompute_h1(
    const float* __restrict__ zu, const float* __restrict__ zm,
    const float* __restrict__ W1, const float* __restrict__ b1,
    char* __restrict__ h1u8, char* __restrict__ h1m8,
    int Mu, int Mm, int bu)
{
    __shared__ __align__(16) char Bs[32768];
    const int tid  = threadIdx.x;
    const int wid  = tid >> 6;
    const int lane = tid & 63;
    const int g    = lane >> 4;
    const int lm   = lane & 15;

    const bool isU = (int)blockIdx.x < bu;
    const float* z = isU ? zu : zm;
    char* h1       = isU ? h1u8 : h1m8;
    const int M    = isU ? Mu : Mm;
    const int koff = isU ? 0 : 128;
    const int rbase = (isU ? blockIdx.x : blockIdx.x - bu) * 256 + wid * 64;

    // stage W1[:, koff:koff+128] f32 -> bf16 swizzled (2048 chunks of 8 elems)
#pragma unroll
    for (int it = 0; it < 8; ++it) {
        int c  = it * 256 + tid;
        int n  = c >> 4;
        int kc = c & 15;
        const float* src = W1 + n * 256 + koff + kc * 8;
        f32x4 a = *reinterpret_cast<const f32x4*>(src);
        f32x4 b = *reinterpret_cast<const f32x4*>(src + 4);
        *reinterpret_cast<bf16x8*>(&Bs[swz256(n, kc * 16)]) = cvt8(a, b);
    }
    __syncthreads();

    // lane's n = nt*16 + lm ; pre-scale folded bias by INV_SU
    float bs[8];
#pragma unroll
    for (int nt = 0; nt < 8; ++nt) bs[nt] = 0.5f * INV_SU * b1[nt * 16 + lm];

    f32x4 acc[4][8];
#pragma unroll
    for (int mt = 0; mt < 4; ++mt)
#pragma unroll
        for (int nt = 0; nt < 8; ++nt) acc[mt][nt] = f32x4{0.f, 0.f, 0.f, 0.f};

#pragma unroll
    for (int ks = 0; ks < 4; ++ks) {
        bf16x8 a[4];
#pragma unroll
        for (int mt = 0; mt < 4; ++mt) {
            int r = rbase + mt * 16 + lm;
            r = r < M ? r : M - 1;
            const float* p = z + (size_t)r * 128 + ks * 32 + g * 8;
            f32x4 x0 = *reinterpret_cast<const f32x4*>(p);
            f32x4 x1 = *reinterpret_cast<const f32x4*>(p + 4);
            a[mt] = cvt8(x0, x1);
        }
        const int kbyte = (ks * 32 + g * 8) * 2;
#pragma unroll
        for (int nt = 0; nt < 8; ++nt) {
            bf16x8 bfr = *reinterpret_cast<const bf16x8*>(&Bs[swz256(nt * 16 + lm, kbyte)]);
#pragma unroll
            for (int mt = 0; mt < 4; ++mt)
                acc[mt][nt] = __builtin_amdgcn_mfma_f32_16x16x32_bf16(
                    a[mt], bfr, acc[mt][nt], 0, 0, 0);   // NORMAL order
        }
    }

    // epilogue: m = rbase + mt*16 + g*4 + r ; n = nt*16 + lm ; byte store
#pragma unroll
    for (int mt = 0; mt < 4; ++mt) {
#pragma unroll
        for (int r = 0; r < 4; ++r) {
            const int m = rbase + mt * 16 + g * 4 + r;
            if (m < M) {
                char* dst = h1 + (size_t)m * 128 + lm;
#pragma unroll
                for (int nt = 0; nt < 8; ++nt) {
                    float t = fmaf(acc[mt][nt][r], INV_SU, bs[nt]);
                    float c = fminf(127.f, fmaxf(-127.f, t));
                    float f = c + MAGIC;
                    dst[nt * 16] = (char)(__builtin_bit_cast(uint32_t, f) & 0xFFu);
                }
            }
        }
    }
}

// ---------------------------------------------------------------------------
// edge_score: out[e] = SU * ( max(uq+mq, 0) . w2 ) + b2  (unchanged from R7)
// ---------------------------------------------------------------------------
__global__ __launch_bounds__(256) void edge_score(
    const char* __restrict__ h1u8, const char* __restrict__ h1m8,
    const int* __restrict__ row, const int* __restrict__ col,
    const float* __restrict__ W2, const float* __restrict__ b2,
    float* __restrict__ out, int nE)
{
    const int tid = blockIdx.x * 256 + threadIdx.x;
    const int g   = tid >> 4;
    const int l   = tid & 15;
    const int e0  = g * 8;
    if (e0 >= nE) return;

    float w2s[8];
    {
        f32x4 c0 = *reinterpret_cast<const f32x4*>(W2 + l * 8);
        f32x4 c1 = *reinterpret_cast<const f32x4*>(W2 + l * 8 + 4);
#pragma unroll
        for (int j = 0; j < 4; ++j) { w2s[j] = c0[j] * SU; w2s[4 + j] = c1[j] * SU; }
    }
    const float b2s = b2[0];

    int ridx[8], cidx[8];
    if (e0 + 8 <= nE) {
        i32x4 r0 = __builtin_nontemporal_load(reinterpret_cast<const i32x4*>(row + e0));
        i32x4 r1 = __builtin_nontemporal_load(reinterpret_cast<const i32x4*>(row + e0 + 4));
        i32x4 c0 = __builtin_nontemporal_load(reinterpret_cast<const i32x4*>(col + e0));
        i32x4 c1 = __builtin_nontemporal_load(reinterpret_cast<const i32x4*>(col + e0 + 4));
#pragma unroll
        for (int j = 0; j < 4; ++j) { ridx[j] = r0[j]; ridx[4 + j] = r1[j]; }
#pragma unroll
        for (int j = 0; j < 4; ++j) { cidx[j] = c0[j]; cidx[4 + j] = c1[j]; }
    } else {
#pragma unroll
        for (int j = 0; j < 8; ++j) {
            int e = e0 + j;
            e = e < nE ? e : nE - 1;
            ridx[j] = row[e];
            cidx[j] = col[e];
        }
    }

    // issue all 16 gathers back-to-back, then fence the scheduler
    char8 u[8], m[8];
#pragma unroll
    for (int j = 0; j < 8; ++j)
        u[j] = *reinterpret_cast<const char8*>(h1u8 + (size_t)ridx[j] * 128 + l * 8);
#pragma unroll
    for (int j = 0; j < 8; ++j)
        m[j] = *reinterpret_cast<const char8*>(h1m8 + (size_t)cidx[j] * 128 + l * 8);
    __builtin_amdgcn_sched_barrier(0);

    float s[8];
#pragma unroll
    for (int j = 0; j < 8; ++j) {
        float acc = 0.f;
#pragma unroll
        for (int q = 0; q < 8; ++q) {
            int su = (int)u[j][q] + (int)m[j][q];
            su = su > 0 ? su : 0;
            acc = fmaf((float)su, w2s[q], acc);
        }
        acc += __shfl_xor(acc, 1);
        acc += __shfl_xor(acc, 2);
        acc += __shfl_xor(acc, 4);
        acc += __shfl_xor(acc, 8);
        s[j] = acc + b2s;
    }

    float v = 0.f;
#pragma unroll
    for (int j = 0; j < 8; ++j) v = (l == j) ? s[j] : v;
    const int e = e0 + l;
    if (l < 8 && e < nE) __builtin_nontemporal_store(v, out + e);
}

// ---------------------------------------------------------------------------
// fallback (no workspace): round-0 fused kernel, f32 gather path
// ---------------------------------------------------------------------------
__device__ __forceinline__ unsigned swzB(int n, int kbyte) {
    return ((unsigned)(n * 512 + kbyte)) ^ (unsigned)((n & 7) << 4);
}

__global__ __launch_bounds__(256, 2) void edge_mlp_fallback(
    const float* __restrict__ z_user, const float* __restrict__ z_movie,
    const int* __restrict__ row, const int* __restrict__ col,
    const float* __restrict__ W1, const float* __restrict__ b1,
    const float* __restrict__ W2, const float* __restrict__ b2,
    float* __restrict__ out, int nE, int ntiles)
{
    __shared__ __align__(16) char Bs[65536];
    const int tid  = threadIdx.x;
    const int wid  = tid >> 6;
    const int lane = tid & 63;
    const int g    = lane >> 4;
    const int lm   = lane & 15;

#pragma unroll
    for (int it = 0; it < 16; ++it) {
        int c  = it * 256 + tid;
        int n  = c >> 5;
        int kc = c & 31;
        const float* src = W1 + n * 256 + kc * 8;
        f32x4 a = *reinterpret_cast<const f32x4*>(src);
        f32x4 b = *reinterpret_cast<const f32x4*>(src + 4);
        *reinterpret_cast<bf16x8*>(&Bs[swzB(n, kc * 16)]) = cvt8(a, b);
    }
    __syncthreads();

    float b1v[8], w2v[8];
#pragma unroll
    for (int nt = 0; nt < 8; ++nt) {
        int n = nt * 16 + lm;
        b1v[nt] = b1[n];
        w2v[nt] = W2[n];
    }
    const float b2s = b2[0];

    for (int tile = blockIdx.x; tile < ntiles; tile += gridDim.x) {
        const int ebase = tile * 256 + wid * 64;
        int re[4], ce[4];
#pragma unroll
        for (int mt = 0; mt < 4; ++mt) {
            int e = ebase + mt * 16 + lm;
            e = e < nE ? e : nE - 1;
            re[mt] = row[e];
            ce[mt] = col[e];
        }
        f32x4 acc[4][8];
#pragma unroll
        for (int mt = 0; mt < 4; ++mt)
#pragma unroll
            for (int nt = 0; nt < 8; ++nt) acc[mt][nt] = f32x4{0.f, 0.f, 0.f, 0.f};
#pragma unroll
        for (int half = 0; half < 2; ++half) {
#pragma unroll
            for (int ks = 0; ks < 4; ++ks) {
                bf16x8 a[4];
#pragma unroll
                for (int mt = 0; mt < 4; ++mt) {
                    const float* p = (half ? z_movie + (size_t)ce[mt] * 128
                                           : z_user + (size_t)re[mt] * 128) + ks * 32 + g * 8;
                    f32x4 x0 = *reinterpret_cast<const f32x4*>(p);
                    f32x4 x1 = *reinterpret_cast<const f32x4*>(p + 4);
                    a[mt] = cvt8(x0, x1);
                }
                const int kbyte = (half * 128 + ks * 32 + g * 8) * 2;
#pragma unroll
                for (int nt = 0; nt < 8; ++nt) {
                    bf16x8 bfr = *reinterpret_cast<const bf16x8*>(&Bs[swzB(nt * 16 + lm, kbyte)]);
#pragma unroll
                    for (int mt = 0; mt < 4; ++mt)
                        acc[mt][nt] = __builtin_amdgcn_mfma_f32_16x16x32_bf16(
                            a[mt], bfr, acc[mt][nt], 0, 0, 0);
                }
            }
        }
#pragma unroll
        for (int mt = 0; mt < 4; ++mt) {
#pragma unroll
            for (int r = 0; r < 4; ++r) {
                float s = 0.f;
#pragma unroll
                for (int nt = 0; nt < 8; ++nt)
                    s += fmaxf(acc[mt][nt][r] + b1v[nt], 0.f) * w2v[nt];
                s += __shfl_xor(s, 8);
                s += __shfl_xor(s, 4);
                s += __shfl_xor(s, 2);
                s += __shfl_xor(s, 1);
                if (lm == 0) {
                    int e = ebase + mt * 16 + g * 4 + r;
                    if (e < nE) out[e] = s + b2s;
                }
            }
        }
    }
}

extern "C" void kernel_launch(void* const* d_in, const int* in_sizes, int n_in,
                              void* d_out, int out_size, void* d_ws, size_t ws_size,
                              hipStream_t stream) {
    const float* z_user  = (const float*)d_in[0];
    const float* z_movie = (const float*)d_in[1];
    const int*   row     = (const int*)d_in[2];
    const int*   col     = (const int*)d_in[3];
    const float* W1      = (const float*)d_in[4];
    const float* b1      = (const float*)d_in[5];
    const float* W2      = (const float*)d_in[6];
    const float* b2      = (const float*)d_in[7];
    float*       out     = (float*)d_out;

    const int nE = in_sizes[2];
    const int Mu = in_sizes[0] / 128;   // N_USERS
    const int Mm = in_sizes[1] / 128;   // N_MOVIES

    const size_t need = ((size_t)Mu + (size_t)Mm) * 128;   // both tables int8

    if (ws_size >= need) {
        char* h1u8 = (char*)d_ws;
        char* h1m8 = h1u8 + (size_t)Mu * 128;

        const int bu = (Mu + 255) / 256;
        const int bm = (Mm + 255) / 256;
        precompute_h1<<<bu + bm, 256, 0, stream>>>(z_user, z_movie, W1, b1,
                                                   h1u8, h1m8, Mu, Mm, bu);

        const int nGroups = (nE + 7) / 8;
        const int blocks  = (nGroups * 16 + 255) / 256;
        edge_score<<<blocks, 256, 0, stream>>>(h1u8, h1m8, row, col,
                                               W2, b2, out, nE);
    } else {
        const int ntiles = (nE + 255) / 256;
        const int grid   = ntiles < 512 ? ntiles : 512;
        edge_mlp_fallback<<<grid, 256, 0, stream>>>(z_user, z_movie, row, col,
                                                    W1, b1, W2, b2, out, nE, ntiles);
    }
}

// Round 12
// 60.549 us; speedup vs baseline: 1.1974x; 1.0375x over previous
//
#include <hip/hip_runtime.h>
#include <stdint.h>

typedef __attribute__((ext_vector_type(8))) short bf16x8;
typedef __attribute__((ext_vector_type(8))) char  char8;
typedef __attribute__((ext_vector_type(4))) float f32x4;
typedef __attribute__((ext_vector_type(4))) int   i32x4;

#define SU      (4.5f / 127.0f)     // shared int8 scale for both h1 tables
#define INV_SU  (127.0f / 4.5f)
#define MAGIC   12582912.0f         // 1.5 * 2^23 : RNE int-round via add
#define ZSTRIDE 80                  // LDS bytes per row-slice (64 data + 16 pad)

__device__ __forceinline__ unsigned short f2bf(float f) {
    uint32_t u = __builtin_bit_cast(uint32_t, f);
    uint32_t r = (u + 0x7FFFu + ((u >> 16) & 1u)) >> 16;  // RTN-even
    return (unsigned short)r;
}

__device__ __forceinline__ bf16x8 cvt8(f32x4 a, f32x4 b) {
    bf16x8 v;
#pragma unroll
    for (int i = 0; i < 4; ++i) v[i] = (short)f2bf(a[i]);
#pragma unroll
    for (int i = 0; i < 4; ++i) v[4 + i] = (short)f2bf(b[i]);
    return v;
}

// swizzled byte offset inside a [128][128] bf16 LDS tile (row = 256 B)
__device__ __forceinline__ unsigned swz256(int n, int kbyte) {
    return ((unsigned)(n * 256 + kbyte)) ^ (unsigned)((n & 7) << 4);
}

// ---------------------------------------------------------------------------
// precompute_h1 v6: COALESCED z staging. Per K-slice (32 f32), all 256 rows
// are loaded cooperatively (4 thr/row, contiguous 128 B segments), cvt'd to
// bf16 once, staged in LDS (stride 80 B -> 2-way banks = free), then A-frags
// come from ds_read_b128. Fixes the 16-row-scatter per A-load that kept every
// previous variant latency-bound at ~42 us. LDS 52 KB -> 3 blocks/CU.
// Same MFMA order + R10 magic-quant epilogue -> bit-identical h1 tables.
// ---------------------------------------------------------------------------
__global__ __launch_bounds__(256) void precompute_h1(
    const float* __restrict__ zu, const float* __restrict__ zm,
    const float* __restrict__ W1, const float* __restrict__ b1,
    char* __restrict__ h1u8, char* __restrict__ h1m8,
    int Mu, int Mm, int bu)
{
    __shared__ __align__(16) char Bs[32768];
    __shared__ __align__(16) char Zs[256 * ZSTRIDE];
    const int tid  = threadIdx.x;
    const int wid  = tid >> 6;
    const int lane = tid & 63;
    const int g    = lane >> 4;
    const int lm   = lane & 15;

    const bool isU = (int)blockIdx.x < bu;
    const float* z = isU ? zu : zm;
    char* h1       = isU ? h1u8 : h1m8;
    const int M    = isU ? Mu : Mm;
    const int koff = isU ? 0 : 128;
    const int rbase0 = (isU ? blockIdx.x : blockIdx.x - bu) * 256;
    const int rbase  = rbase0 + wid * 64;

    // stage W1[:, koff:koff+128] f32 -> bf16 swizzled (2048 chunks of 8 elems)
#pragma unroll
    for (int it = 0; it < 8; ++it) {
        int c  = it * 256 + tid;
        int n  = c >> 4;
        int kc = c & 15;
        const float* src = W1 + n * 256 + koff + kc * 8;
        f32x4 a = *reinterpret_cast<const f32x4*>(src);
        f32x4 b = *reinterpret_cast<const f32x4*>(src + 4);
        *reinterpret_cast<bf16x8*>(&Bs[swz256(n, kc * 16)]) = cvt8(a, b);
    }
    __syncthreads();

    // lane's n = nt*16 + lm ; pre-scale folded bias by INV_SU
    float bs[8];
#pragma unroll
    for (int nt = 0; nt < 8; ++nt) bs[nt] = 0.5f * INV_SU * b1[nt * 16 + lm];

    f32x4 acc[4][8];
#pragma unroll
    for (int mt = 0; mt < 4; ++mt)
#pragma unroll
        for (int nt = 0; nt < 8; ++nt) acc[mt][nt] = f32x4{0.f, 0.f, 0.f, 0.f};

    const int part = tid & 3;        // 4 threads per row-slice
    const int rsub = tid >> 2;       // 0..63

#pragma unroll
    for (int s = 0; s < 4; ++s) {
        // ---- coalesced stage of slice s: z[rbase0..+256][s*32..+32] -> Zs ----
#pragma unroll
        for (int rd = 0; rd < 4; ++rd) {
            const int lrow = rd * 64 + rsub;
            int grow = rbase0 + lrow;
            grow = grow < M ? grow : M - 1;
            const float* p = z + (size_t)grow * 128 + s * 32 + part * 8;
            f32x4 x0 = *reinterpret_cast<const f32x4*>(p);
            f32x4 x1 = *reinterpret_cast<const f32x4*>(p + 4);
            *reinterpret_cast<bf16x8*>(&Zs[lrow * ZSTRIDE + part * 16]) = cvt8(x0, x1);
        }
        __syncthreads();

        // ---- A-frags from LDS, MFMA ----
        bf16x8 a[4];
#pragma unroll
        for (int mt = 0; mt < 4; ++mt)
            a[mt] = *reinterpret_cast<const bf16x8*>(
                &Zs[(wid * 64 + mt * 16 + lm) * ZSTRIDE + g * 16]);

        const int kbyte = (s * 32 + g * 8) * 2;
#pragma unroll
        for (int nt = 0; nt < 8; ++nt) {
            bf16x8 bfr = *reinterpret_cast<const bf16x8*>(&Bs[swz256(nt * 16 + lm, kbyte)]);
#pragma unroll
            for (int mt = 0; mt < 4; ++mt)
                acc[mt][nt] = __builtin_amdgcn_mfma_f32_16x16x32_bf16(
                    a[mt], bfr, acc[mt][nt], 0, 0, 0);   // NORMAL order
        }
        __syncthreads();   // slice buffer reused next iteration
    }

    // epilogue: m = rbase + mt*16 + g*4 + r ; n = nt*16 + lm ; byte store
#pragma unroll
    for (int mt = 0; mt < 4; ++mt) {
#pragma unroll
        for (int r = 0; r < 4; ++r) {
            const int m = rbase + mt * 16 + g * 4 + r;
            if (m < M) {
                char* dst = h1 + (size_t)m * 128 + lm;
#pragma unroll
                for (int nt = 0; nt < 8; ++nt) {
                    float t = fmaf(acc[mt][nt][r], INV_SU, bs[nt]);
                    float c = fminf(127.f, fmaxf(-127.f, t));
                    float f = c + MAGIC;
                    dst[nt * 16] = (char)(__builtin_bit_cast(uint32_t, f) & 0xFFu);
                }
            }
        }
    }
}

// ---------------------------------------------------------------------------
// edge_score: out[e] = SU * ( max(uq+mq, 0) . w2 ) + b2  (unchanged from R7)
// ---------------------------------------------------------------------------
__global__ __launch_bounds__(256) void edge_score(
    const char* __restrict__ h1u8, const char* __restrict__ h1m8,
    const int* __restrict__ row, const int* __restrict__ col,
    const float* __restrict__ W2, const float* __restrict__ b2,
    float* __restrict__ out, int nE)
{
    const int tid = blockIdx.x * 256 + threadIdx.x;
    const int g   = tid >> 4;
    const int l   = tid & 15;
    const int e0  = g * 8;
    if (e0 >= nE) return;

    float w2s[8];
    {
        f32x4 c0 = *reinterpret_cast<const f32x4*>(W2 + l * 8);
        f32x4 c1 = *reinterpret_cast<const f32x4*>(W2 + l * 8 + 4);
#pragma unroll
        for (int j = 0; j < 4; ++j) { w2s[j] = c0[j] * SU; w2s[4 + j] = c1[j] * SU; }
    }
    const float b2s = b2[0];

    int ridx[8], cidx[8];
    if (e0 + 8 <= nE) {
        i32x4 r0 = __builtin_nontemporal_load(reinterpret_cast<const i32x4*>(row + e0));
        i32x4 r1 = __builtin_nontemporal_load(reinterpret_cast<const i32x4*>(row + e0 + 4));
        i32x4 c0 = __builtin_nontemporal_load(reinterpret_cast<const i32x4*>(col + e0));
        i32x4 c1 = __builtin_nontemporal_load(reinterpret_cast<const i32x4*>(col + e0 + 4));
#pragma unroll
        for (int j = 0; j < 4; ++j) { ridx[j] = r0[j]; ridx[4 + j] = r1[j]; }
#pragma unroll
        for (int j = 0; j < 4; ++j) { cidx[j] = c0[j]; cidx[4 + j] = c1[j]; }
    } else {
#pragma unroll
        for (int j = 0; j < 8; ++j) {
            int e = e0 + j;
            e = e < nE ? e : nE - 1;
            ridx[j] = row[e];
            cidx[j] = col[e];
        }
    }

    // issue all 16 gathers back-to-back, then fence the scheduler
    char8 u[8], m[8];
#pragma unroll
    for (int j = 0; j < 8; ++j)
        u[j] = *reinterpret_cast<const char8*>(h1u8 + (size_t)ridx[j] * 128 + l * 8);
#pragma unroll
    for (int j = 0; j < 8; ++j)
        m[j] = *reinterpret_cast<const char8*>(h1m8 + (size_t)cidx[j] * 128 + l * 8);
    __builtin_amdgcn_sched_barrier(0);

    float s[8];
#pragma unroll
    for (int j = 0; j < 8; ++j) {
        float acc = 0.f;
#pragma unroll
        for (int q = 0; q < 8; ++q) {
            int su = (int)u[j][q] + (int)m[j][q];
            su = su > 0 ? su : 0;
            acc = fmaf((float)su, w2s[q], acc);
        }
        acc += __shfl_xor(acc, 1);
        acc += __shfl_xor(acc, 2);
        acc += __shfl_xor(acc, 4);
        acc += __shfl_xor(acc, 8);
        s[j] = acc + b2s;
    }

    float v = 0.f;
#pragma unroll
    for (int j = 0; j < 8; ++j) v = (l == j) ? s[j] : v;
    const int e = e0 + l;
    if (l < 8 && e < nE) __builtin_nontemporal_store(v, out + e);
}

// ---------------------------------------------------------------------------
// fallback (no workspace): round-0 fused kernel, f32 gather path
// ---------------------------------------------------------------------------
__device__ __forceinline__ unsigned swzB(int n, int kbyte) {
    return ((unsigned)(n * 512 + kbyte)) ^ (unsigned)((n & 7) << 4);
}

__global__ __launch_bounds__(256, 2) void edge_mlp_fallback(
    const float* __restrict__ z_user, const float* __restrict__ z_movie,
    const int* __restrict__ row, const int* __restrict__ col,
    const float* __restrict__ W1, const float* __restrict__ b1,
    const float* __restrict__ W2, const float* __restrict__ b2,
    float* __restrict__ out, int nE, int ntiles)
{
    __shared__ __align__(16) char Bs[65536];
    const int tid  = threadIdx.x;
    const int wid  = tid >> 6;
    const int lane = tid & 63;
    const int g    = lane >> 4;
    const int lm   = lane & 15;

#pragma unroll
    for (int it = 0; it < 16; ++it) {
        int c  = it * 256 + tid;
        int n  = c >> 5;
        int kc = c & 31;
        const float* src = W1 + n * 256 + kc * 8;
        f32x4 a = *reinterpret_cast<const f32x4*>(src);
        f32x4 b = *reinterpret_cast<const f32x4*>(src + 4);
        *reinterpret_cast<bf16x8*>(&Bs[swzB(n, kc * 16)]) = cvt8(a, b);
    }
    __syncthreads();

    float b1v[8], w2v[8];
#pragma unroll
    for (int nt = 0; nt < 8; ++nt) {
        int n = nt * 16 + lm;
        b1v[nt] = b1[n];
        w2v[nt] = W2[n];
    }
    const float b2s = b2[0];

    for (int tile = blockIdx.x; tile < ntiles; tile += gridDim.x) {
        const int ebase = tile * 256 + wid * 64;
        int re[4], ce[4];
#pragma unroll
        for (int mt = 0; mt < 4; ++mt) {
            int e = ebase + mt * 16 + lm;
            e = e < nE ? e : nE - 1;
            re[mt] = row[e];
            ce[mt] = col[e];
        }
        f32x4 acc[4][8];
#pragma unroll
        for (int mt = 0; mt < 4; ++mt)
#pragma unroll
            for (int nt = 0; nt < 8; ++nt) acc[mt][nt] = f32x4{0.f, 0.f, 0.f, 0.f};
#pragma unroll
        for (int half = 0; half < 2; ++half) {
#pragma unroll
            for (int ks = 0; ks < 4; ++ks) {
                bf16x8 a[4];
#pragma unroll
                for (int mt = 0; mt < 4; ++mt) {
                    const float* p = (half ? z_movie + (size_t)ce[mt] * 128
                                           : z_user + (size_t)re[mt] * 128) + ks * 32 + g * 8;
                    f32x4 x0 = *reinterpret_cast<const f32x4*>(p);
                    f32x4 x1 = *reinterpret_cast<const f32x4*>(p + 4);
                    a[mt] = cvt8(x0, x1);
                }
                const int kbyte = (half * 128 + ks * 32 + g * 8) * 2;
#pragma unroll
                for (int nt = 0; nt < 8; ++nt) {
                    bf16x8 bfr = *reinterpret_cast<const bf16x8*>(&Bs[swzB(nt * 16 + lm, kbyte)]);
#pragma unroll
                    for (int mt = 0; mt < 4; ++mt)
                        acc[mt][nt] = __builtin_amdgcn_mfma_f32_16x16x32_bf16(
                            a[mt], bfr, acc[mt][nt], 0, 0, 0);
                }
            }
        }
#pragma unroll
        for (int mt = 0; mt < 4; ++mt) {
#pragma unroll
            for (int r = 0; r < 4; ++r) {
                float s = 0.f;
#pragma unroll
                for (int nt = 0; nt < 8; ++nt)
                    s += fmaxf(acc[mt][nt][r] + b1v[nt], 0.f) * w2v[nt];
                s += __shfl_xor(s, 8);
                s += __shfl_xor(s, 4);
                s += __shfl_xor(s, 2);
                s += __shfl_xor(s, 1);
                if (lm == 0) {
                    int e = ebase + mt * 16 + g * 4 + r;
                    if (e < nE) out[e] = s + b2s;
                }
            }
        }
    }
}

extern "C" void kernel_launch(void* const* d_in, const int* in_sizes, int n_in,
                              void* d_out, int out_size, void* d_ws, size_t ws_size,
                              hipStream_t stream) {
    const float* z_user  = (const float*)d_in[0];
    const float* z_movie = (const float*)d_in[1];
    const int*   row     = (const int*)d_in[2];
    const int*   col     = (const int*)d_in[3];
    const float* W1      = (const float*)d_in[4];
    const float* b1      = (const float*)d_in[5];
    const float* W2      = (const float*)d_in[6];
    const float* b2      = (const float*)d_in[7];
    float*       out     = (float*)d_out;

    const int nE = in_sizes[2];
    const int Mu = in_sizes[0] / 128;   // N_USERS
    const int Mm = in_sizes[1] / 128;   // N_MOVIES

    const size_t need = ((size_t)Mu + (size_t)Mm) * 128;   // both tables int8

    if (ws_size >= need) {
        char* h1u8 = (char*)d_ws;
        char* h1m8 = h1u8 + (size_t)Mu * 128;

        const int bu = (Mu + 255) / 256;
        const int bm = (Mm + 255) / 256;
        precompute_h1<<<bu + bm, 256, 0, stream>>>(z_user, z_movie, W1, b1,
                                                   h1u8, h1m8, Mu, Mm, bu);

        const int nGroups = (nE + 7) / 8;
        const int blocks  = (nGroups * 16 + 255) / 256;
        edge_score<<<blocks, 256, 0, stream>>>(h1u8, h1m8, row, col,
                                               W2, b2, out, nE);
    } else {
        const int ntiles = (nE + 255) / 256;
        const int grid   = ntiles < 512 ? ntiles : 512;
        edge_mlp_fallback<<<grid, 256, 0, stream>>>(z_user, z_movie, row, col,
                                                    W1, b1, W2, b2, out, nE, ntiles);
    }
}